// Round 10
// baseline (678.358 us; speedup 1.0000x reference)
//
#include <hip/hip_runtime.h>

// ---------------------------------------------------------------------------
// MultiheadSelfAttentionRoPE  (f32 inputs -> **f32 output**)
//   B=2, S=2048, D=2048, H=16, dk=128, causal, RoPE interleaved pairs.
// Pipeline (v11):
//   0) cast (grid.z=5): x, Wq, Wk, Wv, Wo  f32 -> bf16 workspace copies
//   1) gemm256 (grid.z=3): Q,K,V = x @ W{q,k,v}^T  [4096x2048] bf16
//      EXACT v5 kernel (measured 125-132 us, SQ_LDS_BANK_CONFLICT == 0).
//   2) rope_vtrans (merged, grid.z 0..63): z<32 -> vtrans slice (V -> Vt),
//      z>=32 -> rope slice (in-place RoPE on Q,K).  One launch instead of
//      two serial ones; the two memory-bound sweeps are independent
//      (Q/K vs V) and share the machine.
//   3) attn: flash MFMA attention v4 (defer-max), launch_bounds (256,3):
//      48 KB LDS x 3 = 144 <= 160 KB, VGPR budget 170 >= ~160 live state.
//      3 co-resident blocks/CU give cross-block overlap (m114) during the
//      serial barrier+LDS-write phase of each kv-tile.
//   4) gemm128<float> (grid.z=1): out = Ab @ Wo^T -> d_out (f32 stores),
//      256 blocks = 1 full round (v8, verified).
// Workspace: xb 16.78 + 4*Wb 33.55 + Q/K/V 50.33 = 100.7 MB.
// ---------------------------------------------------------------------------

#define AS1 __attribute__((address_space(1)))
#define AS3 __attribute__((address_space(3)))

typedef __bf16 bf16;
typedef float f32x4 __attribute__((ext_vector_type(4)));
typedef bf16 bf16x8 __attribute__((ext_vector_type(8)));
typedef bf16 bf16x4 __attribute__((ext_vector_type(4)));
typedef bf16 bf16x2 __attribute__((ext_vector_type(2)));

#define SEQ 2048
#define DMODEL 2048
#define NH 16
#define DK 128

// ---------------------------------------------------------------------------
// Cast f32 -> bf16.  z=0: x (8.4M elems);  z=1..4: weights (4.19M each).
// ---------------------------------------------------------------------------
__global__ __launch_bounds__(256) void cast_f32_bf16(
    const float* __restrict__ s0, const float* __restrict__ s1,
    const float* __restrict__ s2, const float* __restrict__ s3,
    const float* __restrict__ s4,
    bf16* __restrict__ d0, bf16* __restrict__ d1, bf16* __restrict__ d2,
    bf16* __restrict__ d3, bf16* __restrict__ d4)
{
    const int z = blockIdx.z;
    const float* s = (z == 0) ? s0 : (z == 1) ? s1 : (z == 2) ? s2 : (z == 3) ? s3 : s4;
    bf16*        d = (z == 0) ? d0 : (z == 1) ? d1 : (z == 2) ? d2 : (z == 3) ? d3 : d4;
    const int n = (z == 0) ? (4096 * 2048) : (2048 * 2048);
    const int i = (blockIdx.x * 256 + threadIdx.x) * 4;
    if (i >= n) return;
    const f32x4 v = *(const f32x4*)(s + i);
    bf16x4 r;
    r[0] = (bf16)v[0]; r[1] = (bf16)v[1]; r[2] = (bf16)v[2]; r[3] = (bf16)v[3];
    *(bf16x4*)(d + i) = r;
}

// ---------------------------------------------------------------------------
// gemm256 (EXACT v5): C = A @ B^T, 256x256 tile, BK=64, 512 threads
// (8 waves, 2M x 4N).  128 KB dbuf LDS, 2-tile lookahead, vmcnt(8) counted.
//   Swizzle (v5-verified, conflicts==0): logical byte l (row*64 + colb)
//   stored at l ^ (((row>>1)&3)<<4); pre-swizzled global source (linear LDS
//   dest, rule #21) + same XOR on the ds_read side.
//   Per K-tile: vmcnt(8); bar; dsr 12xb128; lgkm0; bar; stage t+2.kk;
//   setprio; 16 MFMA; setprio  (x2 kk halves).
// Verified layouts: A-frag A[m=l16][k=quad*8+j], B-frag B^T[n=l16][k=...],
//   C/D row=quad*4+reg, col=l16.
// ---------------------------------------------------------------------------
__global__ __launch_bounds__(512, 2) void gemm256(
    const bf16* __restrict__ A,
    const bf16* __restrict__ B0, const bf16* __restrict__ B1, const bf16* __restrict__ B2,
    bf16* __restrict__ C0, bf16* __restrict__ C1, bf16* __restrict__ C2,
    int M, int N, int K)
{
    const bf16* Bp = (blockIdx.z == 0) ? B0 : ((blockIdx.z == 1) ? B1 : B2);
    bf16* C = (blockIdx.z == 0) ? C0 : ((blockIdx.z == 1) ? C1 : C2);

    __shared__ __align__(16) char lds[131072];   // [buf][A 32K | B 32K]

    // bijective XCD chunk swizzle within each z-slice (nwg=128, 128%8==0)
    const int wg  = blockIdx.y * 8 + blockIdx.x;        // linear, x fastest
    const int swz = (wg & 7) * 16 + (wg >> 3);
    const int n0  = (swz & 7) * 256;
    const int m0  = (swz >> 3) * 256;

    const int tid  = threadIdx.x;
    const int lane = tid & 63;
    const int wave = tid >> 6;
    const int wm   = wave >> 2;        // 0..1
    const int wn   = wave & 3;         // 0..3
    const int l16  = lane & 15;
    const int quad = lane >> 4;

    f32x4 acc[8][4] = {};

    // ---- staging geometry: row rA = tid>>2 (64 B rows), slot (tid&3);
    // source col pre-swizzled by the involution key (rA>>1)&3 == (tid>>3)&3.
    const int rA   = tid >> 2;                               // 0..127
    const int colE = 8 * ((tid & 3) ^ ((tid >> 3) & 3));     // pre-swizzled src col
    const bf16* pA0 = A  + (size_t)(m0 + rA) * K + colE;
    const bf16* pA1 = pA0 + (size_t)128 * K;
    const bf16* pB0 = Bp + (size_t)(n0 + rA) * K + colE;
    const bf16* pB1 = pB0 + (size_t)128 * K;
    const unsigned dstT = (unsigned)(wave * 1024 + lane * 16);
    AS3 char* ldsC = (AS3 char*)lds;

#define GLDS(src, off) \
    __builtin_amdgcn_global_load_lds((const AS1 void*)(src), (AS3 void*)(ldsC + (off)), 16, 0, 0)

    // ---- ds_read bases (swizzled): row bits 1-2 == l16 bits 1-2 for all
    // fragment rows (m*16 / n*16 / wave offsets don't touch bits 1-2) ----
    const int cOff = (quad * 16) ^ (((l16 >> 1) & 3) << 4);
    const char* sArd = (const char*)lds + (size_t)(wm * 128 + l16) * 64 + cOff;
    const char* sBrd = (const char*)lds + 32768 + (size_t)(wn * 64 + l16) * 64 + cOff;

    // ---- prologue: stage tiles 0 (buf0) and 1 (buf1) : 16 loads ----
#pragma unroll
    for (int t = 0; t < 2; t++)
#pragma unroll
        for (int kk = 0; kk < 2; kk++) {
            const size_t g = (size_t)(t * 64 + kk * 32);
            const unsigned d = (unsigned)(t * 65536 + kk * 16384) + dstT;
            GLDS(pA0 + g, d);          GLDS(pA1 + g, d + 8192);
            GLDS(pB0 + g, d + 32768);  GLDS(pB1 + g, d + 40960);
        }

#define KTILE(T, VMSTR, DOSTAGE)                                              \
    {                                                                         \
        asm volatile("s_waitcnt " VMSTR ::: "memory");                        \
        __builtin_amdgcn_s_barrier();                                         \
        __builtin_amdgcn_sched_barrier(0);                                    \
        const int cur_ = (T) & 1;                                             \
        const char* aB_ = sArd + cur_ * 65536;                                \
        const char* bB_ = sBrd + cur_ * 65536;                                \
        bf16x8 af[8], bfr[4];                                                 \
        _Pragma("unroll") for (int m = 0; m < 8; m++)                         \
            af[m] = *(const bf16x8*)(aB_ + m * 1024);                         \
        _Pragma("unroll") for (int n = 0; n < 4; n++)                         \
            bfr[n] = *(const bf16x8*)(bB_ + n * 1024);                        \
        asm volatile("s_waitcnt lgkmcnt(0)" ::: "memory");                    \
        __builtin_amdgcn_s_barrier();                                         \
        __builtin_amdgcn_sched_barrier(0);                                    \
        if (DOSTAGE) {                                                        \
            const size_t g_ = (size_t)((T) + 2) * 64;                         \
            const unsigned d_ = (unsigned)(cur_ * 65536) + dstT;              \
            GLDS(pA0 + g_, d_);          GLDS(pA1 + g_, d_ + 8192);           \
            GLDS(pB0 + g_, d_ + 32768);  GLDS(pB1 + g_, d_ + 40960);          \
        }                                                                     \
        __builtin_amdgcn_s_setprio(1);                                        \
        _Pragma("unroll") for (int m = 0; m < 8; m++)                         \
            _Pragma("unroll") for (int n = 0; n < 4; n++)                     \
                acc[m][n] = __builtin_amdgcn_mfma_f32_16x16x32_bf16(af[m], bfr[n], acc[m][n], 0, 0, 0); \
        __builtin_amdgcn_s_setprio(0);                                        \
        _Pragma("unroll") for (int m = 0; m < 8; m++)                         \
            af[m] = *(const bf16x8*)(aB_ + 16384 + m * 1024);                 \
        _Pragma("unroll") for (int n = 0; n < 4; n++)                         \
            bfr[n] = *(const bf16x8*)(bB_ + 16384 + n * 1024);                \
        asm volatile("s_waitcnt lgkmcnt(0)" ::: "memory");                    \
        __builtin_amdgcn_s_barrier();                                         \
        __builtin_amdgcn_sched_barrier(0);                                    \
        if (DOSTAGE) {                                                        \
            const size_t g_ = (size_t)((T) + 2) * 64 + 32;                    \
            const unsigned d_ = (unsigned)(cur_ * 65536 + 16384) + dstT;      \
            GLDS(pA0 + g_, d_);          GLDS(pA1 + g_, d_ + 8192);           \
            GLDS(pB0 + g_, d_ + 32768);  GLDS(pB1 + g_, d_ + 40960);          \
        }                                                                     \
        __builtin_amdgcn_s_setprio(1);                                        \
        _Pragma("unroll") for (int m = 0; m < 8; m++)                         \
            _Pragma("unroll") for (int n = 0; n < 4; n++)                     \
                acc[m][n] = __builtin_amdgcn_mfma_f32_16x16x32_bf16(af[m], bfr[n], acc[m][n], 0, 0, 0); \
        __builtin_amdgcn_s_setprio(0);                                        \
    }

    const int NTK = K / 64;            // 32
    for (int t = 0; t < NTK - 2; t++)
        KTILE(t, "vmcnt(8)", true);
    KTILE(NTK - 2, "vmcnt(8)", false);
    KTILE(NTK - 1, "vmcnt(0)", false);

#undef KTILE
#undef GLDS

    // ---- epilogue ----
#pragma unroll
    for (int m = 0; m < 8; m++) {
        const int r0 = m0 + wm * 128 + m * 16 + quad * 4;
#pragma unroll
        for (int n = 0; n < 4; n++) {
            const int c = n0 + wn * 64 + n * 16 + l16;
#pragma unroll
            for (int r = 0; r < 4; r++)
                C[(size_t)(r0 + r) * N + c] = (bf16)acc[m][n][r];
        }
    }
}

// ---------------------------------------------------------------------------
// gemm128: C = A @ B^T, 128x256 tile, BK=64, 512 threads (8 waves, 2M x 4N,
// Wm=Wn=64).  (v8, verified; used for the f32-output projection: 256 blocks
// = 1 full round.)
// ---------------------------------------------------------------------------
template <typename CT>
__global__ __launch_bounds__(512, 2) void gemm128(
    const bf16* __restrict__ A,
    const bf16* __restrict__ B0, const bf16* __restrict__ B1, const bf16* __restrict__ B2,
    CT* __restrict__ C0, CT* __restrict__ C1, CT* __restrict__ C2,
    int M, int N, int K)
{
    const bf16* Bp = (blockIdx.z == 0) ? B0 : ((blockIdx.z == 1) ? B1 : B2);
    CT* C = (blockIdx.z == 0) ? C0 : ((blockIdx.z == 1) ? C1 : C2);

    __shared__ __align__(16) char lds[98304];

    const int wg  = blockIdx.y * 8 + blockIdx.x;
    const int swz = (wg & 7) * 32 + (wg >> 3);
    const int n0  = (swz & 7) * 256;
    const int m0  = (swz >> 3) * 128;

    const int tid  = threadIdx.x;
    const int lane = tid & 63;
    const int wave = tid >> 6;
    const int wm   = wave >> 2;
    const int wn   = wave & 3;
    const int l16  = lane & 15;
    const int quad = lane >> 4;

    f32x4 acc[4][4] = {};

    const int rA   = tid >> 2;
    const int colE = 8 * ((tid & 3) ^ ((tid >> 3) & 3));
    const bf16* pA  = A  + (size_t)(m0 + rA) * K + colE;
    const bf16* pB0 = Bp + (size_t)(n0 + rA) * K + colE;
    const bf16* pB1 = pB0 + (size_t)128 * K;
    const unsigned dstT = (unsigned)(tid * 16);
    AS3 char* ldsC = (AS3 char*)lds;

#define GLDS(src, off) \
    __builtin_amdgcn_global_load_lds((const AS1 void*)(src), (AS3 void*)(ldsC + (off)), 16, 0, 0)

    const int cOff = (quad * 16) ^ (((l16 >> 1) & 3) << 4);
    const char* sArd = (const char*)lds + (size_t)(wm * 64 + l16) * 64 + cOff;
    const char* sBrd = (const char*)lds + 16384 + (size_t)(wn * 64 + l16) * 64 + cOff;

#pragma unroll
    for (int t = 0; t < 2; t++)
#pragma unroll
        for (int kk = 0; kk < 2; kk++) {
            const size_t g = (size_t)(t * 64 + kk * 32);
            const unsigned dA = (unsigned)(t * 49152 + kk * 8192) + dstT;
            const unsigned dB = (unsigned)(t * 49152 + 16384 + kk * 16384) + dstT;
            GLDS(pA + g, dA);
            GLDS(pB0 + g, dB);
            GLDS(pB1 + g, dB + 8192);
        }

#define KTILE(T, VMSTR, DOSTAGE)                                              \
    {                                                                         \
        asm volatile("s_waitcnt " VMSTR ::: "memory");                        \
        __builtin_amdgcn_s_barrier();                                         \
        __builtin_amdgcn_sched_barrier(0);                                    \
        const int cur_ = (T) & 1;                                             \
        const char* aB_ = sArd + cur_ * 49152;                                \
        const char* bB_ = sBrd + cur_ * 49152;                                \
        bf16x8 a0[4], b0[4], a1[4], b1[4];                                    \
        _Pragma("unroll") for (int m = 0; m < 4; m++)                         \
            a0[m] = *(const bf16x8*)(aB_ + m * 1024);                         \
        _Pragma("unroll") for (int n = 0; n < 4; n++)                         \
            b0[n] = *(const bf16x8*)(bB_ + n * 1024);                         \
        _Pragma("unroll") for (int m = 0; m < 4; m++)                         \
            a1[m] = *(const bf16x8*)(aB_ + 8192 + m * 1024);                  \
        _Pragma("unroll") for (int n = 0; n < 4; n++)                         \
            b1[n] = *(const bf16x8*)(bB_ + 16384 + n * 1024);                 \
        asm volatile("s_waitcnt lgkmcnt(0)" ::: "memory");                    \
        __builtin_amdgcn_s_barrier();                                         \
        __builtin_amdgcn_sched_barrier(0);                                    \
        if (DOSTAGE) {                                                        \
            const size_t g_ = (size_t)((T) + 2) * 64;                         \
            const unsigned dA_ = (unsigned)(cur_ * 49152) + dstT;             \
            const unsigned dB_ = (unsigned)(cur_ * 49152 + 16384) + dstT;     \
            GLDS(pA + g_, dA_);                                               \
            GLDS(pB0 + g_, dB_);                                              \
            GLDS(pB1 + g_, dB_ + 8192);                                       \
            GLDS(pA + g_ + 32, dA_ + 8192);                                   \
            GLDS(pB0 + g_ + 32, dB_ + 16384);                                 \
            GLDS(pB1 + g_ + 32, dB_ + 24576);                                 \
        }                                                                     \
        __builtin_amdgcn_s_setprio(1);                                        \
        _Pragma("unroll") for (int m = 0; m < 4; m++)                         \
            _Pragma("unroll") for (int n = 0; n < 4; n++)                     \
                acc[m][n] = __builtin_amdgcn_mfma_f32_16x16x32_bf16(a0[m], b0[n], acc[m][n], 0, 0, 0); \
        _Pragma("unroll") for (int m = 0; m < 4; m++)                         \
            _Pragma("unroll") for (int n = 0; n < 4; n++)                     \
                acc[m][n] = __builtin_amdgcn_mfma_f32_16x16x32_bf16(a1[m], b1[n], acc[m][n], 0, 0, 0); \
        __builtin_amdgcn_s_setprio(0);                                        \
    }

    const int NTK = K / 64;
    for (int t = 0; t < NTK - 2; t++)
        KTILE(t, "vmcnt(6)", true);
    KTILE(NTK - 2, "vmcnt(6)", false);
    KTILE(NTK - 1, "vmcnt(0)", false);

#undef KTILE
#undef GLDS

#pragma unroll
    for (int m = 0; m < 4; m++) {
        const int r0 = m0 + wm * 64 + m * 16 + quad * 4;
#pragma unroll
        for (int n = 0; n < 4; n++) {
            const int c = n0 + wn * 64 + n * 16 + l16;
#pragma unroll
            for (int r = 0; r < 4; r++)
                C[(size_t)(r0 + r) * N + c] = (CT)acc[m][n][r];
        }
    }
}

// ---------------------------------------------------------------------------
// rope_vtrans (merged): z<32 -> vtrans slice (bh=z), z>=32 -> rope slice.
// Branch is block-uniform (z), so __syncthreads in the vtrans arm is safe.
// vtrans: V [b*S+s][h*128+d] -> Vt [(b*16+h)*128+d][s]
// rope:   one thread per (s, pair); applies rotation to 4 sites (b x {Q,K}).
// ---------------------------------------------------------------------------
__global__ __launch_bounds__(256) void rope_vtrans(
    bf16* __restrict__ Q, bf16* __restrict__ K,
    const bf16* __restrict__ V, bf16* __restrict__ Vt)
{
    const int z = blockIdx.z;
    if (z < 32) {
        // ---- vtrans ----
        __shared__ bf16 t[32][33];
        const int bh = z;
        const int s0 = blockIdx.x * 32;
        const int d0 = blockIdx.y * 32;
        const int b = bh >> 4, h = bh & 15;
        const int tx = threadIdx.x & 31, ty = threadIdx.x >> 5;

#pragma unroll
        for (int i = 0; i < 4; i++) {
            const int s = s0 + ty + i * 8;
            t[ty + i * 8][tx] = V[(size_t)(b * SEQ + s) * DMODEL + h * DK + d0 + tx];
        }
        __syncthreads();
#pragma unroll
        for (int i = 0; i < 4; i++) {
            const int d = d0 + ty + i * 8;
            Vt[(size_t)(bh * DK + d) * SEQ + s0 + tx] = t[tx][ty + i * 8];
        }
    } else {
        // ---- rope ----
        const int lb  = ((z - 32) * 4 + blockIdx.y) * 64 + blockIdx.x; // 0..8191
        const int idx = lb * 256 + threadIdx.x;
        const int pr  = idx & 1023;
        const int s   = idx >> 10;
        const int p   = pr & 63;

        // log2(10000)/64 = 0.20762050593046836
        const float ph = (float)s * exp2f(-(float)p * 0.20762050593046836f);
        float sn, cs;
        sincosf(ph, &sn, &cs);

#pragma unroll
        for (int t2 = 0; t2 < 2; t2++) {
            bf16* P = t2 ? K : Q;
#pragma unroll
            for (int b = 0; b < 2; b++) {
                bf16* ptr = P + (size_t)(b * SEQ + s) * DMODEL + pr * 2;
                bf16x2 v = *(const bf16x2*)ptr;
                const float x1 = (float)v[0], x2 = (float)v[1];
                bf16x2 r;
                r[0] = (bf16)(x1 * cs - x2 * sn);
                r[1] = (bf16)(x1 * sn + x2 * cs);
                *(bf16x2*)ptr = r;
            }
        }
    }
}

// ---------------------------------------------------------------------------
// Flash-style causal MFMA attention v4 = v3 + defer-max (T13).
// v11: launch_bounds (256,3) -> 3 blocks/CU (LDS 48KB x3 = 144 <= 160 KB).
// ---------------------------------------------------------------------------
#define NEG 3.0e4f

__device__ __forceinline__ bf16* swzK(bf16* base, int row, int bcol) {
    return (bf16*)((char*)base + (((row << 8) + bcol) ^ ((row & 7) << 4)));
}
__device__ __forceinline__ const bf16* swzKc(const bf16* base, int row, int bcol) {
    return (const bf16*)((const char*)base + (((row << 8) + bcol) ^ ((row & 7) << 4)));
}
__device__ __forceinline__ bf16* swzV(bf16* base, int row, int bcol) {
    return (bf16*)((char*)base + (((row << 7) + bcol) ^ ((row & 7) << 4)));
}
__device__ __forceinline__ const bf16* swzVc(const bf16* base, int row, int bcol) {
    return (const bf16*)((const char*)base + (((row << 7) + bcol) ^ ((row & 7) << 4)));
}

__global__ __launch_bounds__(256, 3) void attn(
    const bf16* __restrict__ Q, const bf16* __restrict__ K,
    const bf16* __restrict__ Vt, bf16* __restrict__ O)
{
    const int rev = (blockIdx.y ^ blockIdx.z) & 1;
    const int qt = rev ? (gridDim.x - 1 - blockIdx.x) : blockIdx.x;
    const int h = blockIdx.y, b = blockIdx.z;
    const int tid = threadIdx.x, lane = tid & 63, wave = tid >> 6;
    const int l16 = lane & 15, quad = lane >> 4;

    __shared__ __align__(16) bf16 sK[64 * 128];
    __shared__ __align__(16) bf16 sV[128 * 64];
    __shared__ __align__(16) bf16 sP[4 * 32 * 64];

    const int q0 = qt * 128 + wave * 32;
    bf16* sPw = sP + wave * 2048;

    bf16x8 qf[2][4];
#pragma unroll
    for (int g = 0; g < 2; g++) {
        const bf16* gQ = Q + (size_t)(b * SEQ + q0 + g * 16 + l16) * DMODEL + h * DK + quad * 8;
#pragma unroll
        for (int dc = 0; dc < 4; dc++) qf[g][dc] = *(const bf16x8*)(gQ + dc * 32);
    }

    f32x4 o[2][8] = {};
    float mrow[2] = {-NEG, -NEG};
    float lrow[2] = {0.f, 0.f};

    const bf16* gK = K + (size_t)(b * SEQ) * DMODEL + h * DK;
    const bf16* gV = Vt + (size_t)((b * NH + h) * DK) * SEQ;

    const float scale = 0.12751744154470187f;
    const int nkt = 2 * qt + 2;

    const int rK = tid >> 4;
    const int cK = (tid & 15) * 8;
    const int dV = tid >> 3;
    const int cV = (tid & 7) * 8;

    bf16x8 kreg[4], vreg[4];
    {
#pragma unroll
        for (int i = 0; i < 4; i++)
            kreg[i] = *(const bf16x8*)(gK + (size_t)(rK + 16 * i) * DMODEL + cK);
#pragma unroll
        for (int i = 0; i < 4; i++)
            vreg[i] = *(const bf16x8*)(gV + (size_t)(dV + 32 * i) * SEQ + cV);
    }

    for (int kt = 0; kt < nkt; kt++) {
        __syncthreads();
#pragma unroll
        for (int i = 0; i < 4; i++)
            *(bf16x8*)swzK(sK, rK + 16 * i, cK * 2) = kreg[i];
#pragma unroll
        for (int i = 0; i < 4; i++)
            *(bf16x8*)swzV(sV, dV + 32 * i, cV * 2) = vreg[i];
        __syncthreads();

        if (kt + 1 < nkt) {
            const int kb0 = (kt + 1) * 64;
#pragma unroll
            for (int i = 0; i < 4; i++)
                kreg[i] = *(const bf16x8*)(gK + (size_t)(kb0 + rK + 16 * i) * DMODEL + cK);
#pragma unroll
            for (int i = 0; i < 4; i++)
                vreg[i] = *(const bf16x8*)(gV + (size_t)(dV + 32 * i) * SEQ + kb0 + cV);
        }

        if (kt * 64 <= q0 + 15) {
            f32x4 s4[2][4] = {};
            __builtin_amdgcn_s_setprio(1);
#pragma unroll
            for (int sub = 0; sub < 4; sub++)
#pragma unroll
                for (int dc = 0; dc < 4; dc++) {
                    bf16x8 kb = *(const bf16x8*)swzKc(sK, sub * 16 + l16, dc * 64 + quad * 16);
                    s4[0][sub] = __builtin_amdgcn_mfma_f32_16x16x32_bf16(kb, qf[0][dc], s4[0][sub], 0, 0, 0);
                    s4[1][sub] = __builtin_amdgcn_mfma_f32_16x16x32_bf16(kb, qf[1][dc], s4[1][sub], 0, 0, 0);
                }
            __builtin_amdgcn_s_setprio(0);

#pragma unroll
            for (int g = 0; g < 2; g++) {
                const int qg = q0 + g * 16 + l16;
                const int kb0 = kt * 64 + quad * 4;
                float arr[16];
                float mx = -NEG;
#pragma unroll
                for (int sub = 0; sub < 4; sub++)
#pragma unroll
                    for (int r = 0; r < 4; r++) {
                        const int key = kb0 + sub * 16 + r;
                        const float val = (key <= qg) ? s4[g][sub][r] * scale : -NEG;
                        arr[sub * 4 + r] = val;
                        mx = fmaxf(mx, val);
                    }
                mx = fmaxf(mx, __shfl_xor(mx, 16));
                mx = fmaxf(mx, __shfl_xor(mx, 32));

                // T13 defer-max: rescale only when some row's max grew by >8
                // (P then bounded by 2^8; f32 accum headroom fine).
                float alpha = 1.0f;
                if (__any(mx - mrow[g] > 8.0f)) {
                    const float mnew = fmaxf(mrow[g], mx);
                    alpha = exp2f(mrow[g] - mnew);
                    mrow[g] = mnew;
#pragma unroll
                    for (int r = 0; r < 4; r++) {
                        const float ar = __shfl(alpha, quad * 4 + r, 16);
#pragma unroll
                        for (int dt = 0; dt < 8; dt++) o[g][dt][r] *= ar;
                    }
                }
                float ps = 0.f;
#pragma unroll
                for (int i = 0; i < 16; i++) {
                    arr[i] = exp2f(arr[i] - mrow[g]);
                    ps += arr[i];
                }
                ps += __shfl_xor(ps, 16);
                ps += __shfl_xor(ps, 32);
                lrow[g] = lrow[g] * alpha + ps;

#pragma unroll
                for (int sub = 0; sub < 4; sub++) {
                    bf16x4 pk;
                    pk[0] = (bf16)arr[sub * 4 + 0];
                    pk[1] = (bf16)arr[sub * 4 + 1];
                    pk[2] = (bf16)arr[sub * 4 + 2];
                    pk[3] = (bf16)arr[sub * 4 + 3];
                    *(bf16x4*)swzV(sPw, g * 16 + l16, sub * 32 + quad * 8) = pk;
                }
            }

            asm volatile("s_waitcnt lgkmcnt(0)" ::: "memory");
            __builtin_amdgcn_sched_barrier(0);

            bf16x8 pf0[2], pf1[2];
#pragma unroll
            for (int g = 0; g < 2; g++) {
                pf0[g] = *(const bf16x8*)swzVc(sPw, g * 16 + l16, quad * 16);
                pf1[g] = *(const bf16x8*)swzVc(sPw, g * 16 + l16, 64 + quad * 16);
            }
            __builtin_amdgcn_s_setprio(1);
#pragma unroll
            for (int dt = 0; dt < 8; dt++) {
                bf16x8 vf0 = *(const bf16x8*)swzVc(sV, dt * 16 + l16, quad * 16);
                bf16x8 vf1 = *(const bf16x8*)swzVc(sV, dt * 16 + l16, 64 + quad * 16);
                o[0][dt] = __builtin_amdgcn_mfma_f32_16x16x32_bf16(pf0[0], vf0, o[0][dt], 0, 0, 0);
                o[0][dt] = __builtin_amdgcn_mfma_f32_16x16x32_bf16(pf1[0], vf1, o[0][dt], 0, 0, 0);
                o[1][dt] = __builtin_amdgcn_mfma_f32_16x16x32_bf16(pf0[1], vf0, o[1][dt], 0, 0, 0);
                o[1][dt] = __builtin_amdgcn_mfma_f32_16x16x32_bf16(pf1[1], vf1, o[1][dt], 0, 0, 0);
            }
            __builtin_amdgcn_s_setprio(0);
        }
    }

#pragma unroll
    for (int g = 0; g < 2; g++) {
        bf16* gO = O + (size_t)(b * SEQ + q0 + g * 16 + quad * 4) * DMODEL + h * DK + l16;
#pragma unroll
        for (int r = 0; r < 4; r++) {
            const float lr = __shfl(lrow[g], quad * 4 + r, 16);
            const float inv = 1.0f / lr;
#pragma unroll
            for (int dt = 0; dt < 8; dt++)
                gO[(size_t)r * DMODEL + dt * 16] = (bf16)(o[g][dt][r] * inv);
        }
    }
}

// ---------------------------------------------------------------------------
extern "C" void kernel_launch(void* const* d_in, const int* in_sizes, int n_in,
                              void* d_out, int out_size, void* d_ws, size_t ws_size,
                              hipStream_t stream)
{
    const float* x  = (const float*)d_in[0];
    const float* Wq = (const float*)d_in[2];
    const float* Wk = (const float*)d_in[3];
    const float* Wv = (const float*)d_in[4];
    const float* Wo = (const float*)d_in[5];

    const int M = 2 * SEQ;       // 4096
    const int N = DMODEL;        // 2048
    const int Kd = DMODEL;       // 2048
    const size_t tsz = (size_t)M * N;   // 8.4M elems
    const size_t wsz = (size_t)N * Kd;  // 4.2M elems

    // Workspace layout (bf16): xb | Wqb Wkb Wvb Wob | Qb Kb Vb  = 100.7 MB
    bf16* xb  = (bf16*)d_ws;
    bf16* Wqb = xb  + tsz;
    bf16* Wkb = Wqb + wsz;
    bf16* Wvb = Wkb + wsz;
    bf16* Wob = Wvb + wsz;
    bf16* Qb  = Wob + wsz;
    bf16* Kb  = Qb  + tsz;
    bf16* Vb  = Kb  + tsz;
    bf16* Vt  = (bf16*)d_out;    // scratch in d_out; fully overwritten by
                                 // the final f32 GEMM stores
    bf16* Ab  = Vb;              // alias: Vb dead once Vt is built

    // 0) cast all f32 inputs to bf16
    cast_f32_bf16<<<dim3(tsz / 1024, 1, 5), 256, 0, stream>>>(
        x, Wq, Wk, Wv, Wo, xb, Wqb, Wkb, Wvb, Wob);

    // 1) Q,K,V projections: exact-v5 256^2 GEMM (512 threads)
    gemm256<<<dim3(N / 256, M / 256, 3), 512, 0, stream>>>(
        xb, Wqb, Wkb, Wvb, Qb, Kb, Vb, M, N, Kd);

    // 2) merged RoPE (Q,K) + V transpose: z<32 vtrans, z>=32 rope
    rope_vtrans<<<dim3(64, 4, 64), 256, 0, stream>>>(Qb, Kb, Vb, Vt);

    // 3) causal flash attention -> Ab (Vb's storage)
    attn<<<dim3(SEQ / 128, NH, 2), 256, 0, stream>>>(Qb, Kb, Vt, Ab);

    // 4) output projection: gemm128<float>, 256 blocks = 1 full round
    gemm128<float><<<dim3(N / 256, M / 128, 1), 512, 0, stream>>>(
        Ab, Wob, Wob, Wob, (float*)d_out, (float*)d_out, (float*)d_out, M, N, Kd);
}

// Round 11
// 388.360 us; speedup vs baseline: 1.7467x; 1.7467x over previous
//
#include <hip/hip_runtime.h>

// ---------------------------------------------------------------------------
// MultiheadSelfAttentionRoPE  (f32 inputs -> **f32 output**)
//   B=2, S=2048, D=2048, H=16, dk=128, causal, RoPE interleaved pairs.
// Pipeline (v12 = v10 components + rope_vtrans merge; attn reverted to
// (256,2) after v11's (256,3) caused accumulator spill: FETCH 361MB,
// WRITE 200MB scratch traffic, attn 125->376 us):
//   0) cast (grid.z=5): x, Wq, Wk, Wv, Wo  f32 -> bf16 workspace copies
//   1) gemm256 (grid.z=3): Q,K,V = x @ W{q,k,v}^T  [4096x2048] bf16
//      EXACT v5 kernel (measured 125-132 us, SQ_LDS_BANK_CONFLICT == 0).
//   2) rope_vtrans (merged): z<32 -> vtrans slice, z>=32 -> rope slice.
//   3) attn: flash MFMA attention v4 (defer-max), launch_bounds (256,2)
//      -- the r8/r9-verified configuration.
//   4) gemm128<float> (grid.z=1): out = Ab @ Wo^T -> d_out (f32 stores),
//      256 blocks = 1 full round (v8, verified).
// Workspace: xb 16.78 + 4*Wb 33.55 + Q/K/V 50.33 = 100.7 MB.
// ---------------------------------------------------------------------------

#define AS1 __attribute__((address_space(1)))
#define AS3 __attribute__((address_space(3)))

typedef __bf16 bf16;
typedef float f32x4 __attribute__((ext_vector_type(4)));
typedef bf16 bf16x8 __attribute__((ext_vector_type(8)));
typedef bf16 bf16x4 __attribute__((ext_vector_type(4)));
typedef bf16 bf16x2 __attribute__((ext_vector_type(2)));

#define SEQ 2048
#define DMODEL 2048
#define NH 16
#define DK 128

// ---------------------------------------------------------------------------
// Cast f32 -> bf16.  z=0: x (8.4M elems);  z=1..4: weights (4.19M each).
// ---------------------------------------------------------------------------
__global__ __launch_bounds__(256) void cast_f32_bf16(
    const float* __restrict__ s0, const float* __restrict__ s1,
    const float* __restrict__ s2, const float* __restrict__ s3,
    const float* __restrict__ s4,
    bf16* __restrict__ d0, bf16* __restrict__ d1, bf16* __restrict__ d2,
    bf16* __restrict__ d3, bf16* __restrict__ d4)
{
    const int z = blockIdx.z;
    const float* s = (z == 0) ? s0 : (z == 1) ? s1 : (z == 2) ? s2 : (z == 3) ? s3 : s4;
    bf16*        d = (z == 0) ? d0 : (z == 1) ? d1 : (z == 2) ? d2 : (z == 3) ? d3 : d4;
    const int n = (z == 0) ? (4096 * 2048) : (2048 * 2048);
    const int i = (blockIdx.x * 256 + threadIdx.x) * 4;
    if (i >= n) return;
    const f32x4 v = *(const f32x4*)(s + i);
    bf16x4 r;
    r[0] = (bf16)v[0]; r[1] = (bf16)v[1]; r[2] = (bf16)v[2]; r[3] = (bf16)v[3];
    *(bf16x4*)(d + i) = r;
}

// ---------------------------------------------------------------------------
// gemm256 (EXACT v5): C = A @ B^T, 256x256 tile, BK=64, 512 threads
// (8 waves, 2M x 4N).  128 KB dbuf LDS, 2-tile lookahead, vmcnt(8) counted.
//   Swizzle (v5-verified, conflicts==0): logical byte l (row*64 + colb)
//   stored at l ^ (((row>>1)&3)<<4); pre-swizzled global source (linear LDS
//   dest, rule #21) + same XOR on the ds_read side.
//   Per K-tile: vmcnt(8); bar; dsr 12xb128; lgkm0; bar; stage t+2.kk;
//   setprio; 16 MFMA; setprio  (x2 kk halves).
// Verified layouts: A-frag A[m=l16][k=quad*8+j], B-frag B^T[n=l16][k=...],
//   C/D row=quad*4+reg, col=l16.
// ---------------------------------------------------------------------------
__global__ __launch_bounds__(512, 2) void gemm256(
    const bf16* __restrict__ A,
    const bf16* __restrict__ B0, const bf16* __restrict__ B1, const bf16* __restrict__ B2,
    bf16* __restrict__ C0, bf16* __restrict__ C1, bf16* __restrict__ C2,
    int M, int N, int K)
{
    const bf16* Bp = (blockIdx.z == 0) ? B0 : ((blockIdx.z == 1) ? B1 : B2);
    bf16* C = (blockIdx.z == 0) ? C0 : ((blockIdx.z == 1) ? C1 : C2);

    __shared__ __align__(16) char lds[131072];   // [buf][A 32K | B 32K]

    // bijective XCD chunk swizzle within each z-slice (nwg=128, 128%8==0)
    const int wg  = blockIdx.y * 8 + blockIdx.x;        // linear, x fastest
    const int swz = (wg & 7) * 16 + (wg >> 3);
    const int n0  = (swz & 7) * 256;
    const int m0  = (swz >> 3) * 256;

    const int tid  = threadIdx.x;
    const int lane = tid & 63;
    const int wave = tid >> 6;
    const int wm   = wave >> 2;        // 0..1
    const int wn   = wave & 3;         // 0..3
    const int l16  = lane & 15;
    const int quad = lane >> 4;

    f32x4 acc[8][4] = {};

    // ---- staging geometry: row rA = tid>>2 (64 B rows), slot (tid&3);
    // source col pre-swizzled by the involution key (rA>>1)&3 == (tid>>3)&3.
    const int rA   = tid >> 2;                               // 0..127
    const int colE = 8 * ((tid & 3) ^ ((tid >> 3) & 3));     // pre-swizzled src col
    const bf16* pA0 = A  + (size_t)(m0 + rA) * K + colE;
    const bf16* pA1 = pA0 + (size_t)128 * K;
    const bf16* pB0 = Bp + (size_t)(n0 + rA) * K + colE;
    const bf16* pB1 = pB0 + (size_t)128 * K;
    const unsigned dstT = (unsigned)(wave * 1024 + lane * 16);
    AS3 char* ldsC = (AS3 char*)lds;

#define GLDS(src, off) \
    __builtin_amdgcn_global_load_lds((const AS1 void*)(src), (AS3 void*)(ldsC + (off)), 16, 0, 0)

    // ---- ds_read bases (swizzled): row bits 1-2 == l16 bits 1-2 for all
    // fragment rows (m*16 / n*16 / wave offsets don't touch bits 1-2) ----
    const int cOff = (quad * 16) ^ (((l16 >> 1) & 3) << 4);
    const char* sArd = (const char*)lds + (size_t)(wm * 128 + l16) * 64 + cOff;
    const char* sBrd = (const char*)lds + 32768 + (size_t)(wn * 64 + l16) * 64 + cOff;

    // ---- prologue: stage tiles 0 (buf0) and 1 (buf1) : 16 loads ----
#pragma unroll
    for (int t = 0; t < 2; t++)
#pragma unroll
        for (int kk = 0; kk < 2; kk++) {
            const size_t g = (size_t)(t * 64 + kk * 32);
            const unsigned d = (unsigned)(t * 65536 + kk * 16384) + dstT;
            GLDS(pA0 + g, d);          GLDS(pA1 + g, d + 8192);
            GLDS(pB0 + g, d + 32768);  GLDS(pB1 + g, d + 40960);
        }

#define KTILE(T, VMSTR, DOSTAGE)                                              \
    {                                                                         \
        asm volatile("s_waitcnt " VMSTR ::: "memory");                        \
        __builtin_amdgcn_s_barrier();                                         \
        __builtin_amdgcn_sched_barrier(0);                                    \
        const int cur_ = (T) & 1;                                             \
        const char* aB_ = sArd + cur_ * 65536;                                \
        const char* bB_ = sBrd + cur_ * 65536;                                \
        bf16x8 af[8], bfr[4];                                                 \
        _Pragma("unroll") for (int m = 0; m < 8; m++)                         \
            af[m] = *(const bf16x8*)(aB_ + m * 1024);                         \
        _Pragma("unroll") for (int n = 0; n < 4; n++)                         \
            bfr[n] = *(const bf16x8*)(bB_ + n * 1024);                        \
        asm volatile("s_waitcnt lgkmcnt(0)" ::: "memory");                    \
        __builtin_amdgcn_s_barrier();                                         \
        __builtin_amdgcn_sched_barrier(0);                                    \
        if (DOSTAGE) {                                                        \
            const size_t g_ = (size_t)((T) + 2) * 64;                         \
            const unsigned d_ = (unsigned)(cur_ * 65536) + dstT;              \
            GLDS(pA0 + g_, d_);          GLDS(pA1 + g_, d_ + 8192);           \
            GLDS(pB0 + g_, d_ + 32768);  GLDS(pB1 + g_, d_ + 40960);          \
        }                                                                     \
        __builtin_amdgcn_s_setprio(1);                                        \
        _Pragma("unroll") for (int m = 0; m < 8; m++)                         \
            _Pragma("unroll") for (int n = 0; n < 4; n++)                     \
                acc[m][n] = __builtin_amdgcn_mfma_f32_16x16x32_bf16(af[m], bfr[n], acc[m][n], 0, 0, 0); \
        __builtin_amdgcn_s_setprio(0);                                        \
        _Pragma("unroll") for (int m = 0; m < 8; m++)                         \
            af[m] = *(const bf16x8*)(aB_ + 16384 + m * 1024);                 \
        _Pragma("unroll") for (int n = 0; n < 4; n++)                         \
            bfr[n] = *(const bf16x8*)(bB_ + 16384 + n * 1024);                \
        asm volatile("s_waitcnt lgkmcnt(0)" ::: "memory");                    \
        __builtin_amdgcn_s_barrier();                                         \
        __builtin_amdgcn_sched_barrier(0);                                    \
        if (DOSTAGE) {                                                        \
            const size_t g_ = (size_t)((T) + 2) * 64 + 32;                    \
            const unsigned d_ = (unsigned)(cur_ * 65536 + 16384) + dstT;      \
            GLDS(pA0 + g_, d_);          GLDS(pA1 + g_, d_ + 8192);           \
            GLDS(pB0 + g_, d_ + 32768);  GLDS(pB1 + g_, d_ + 40960);          \
        }                                                                     \
        __builtin_amdgcn_s_setprio(1);                                        \
        _Pragma("unroll") for (int m = 0; m < 8; m++)                         \
            _Pragma("unroll") for (int n = 0; n < 4; n++)                     \
                acc[m][n] = __builtin_amdgcn_mfma_f32_16x16x32_bf16(af[m], bfr[n], acc[m][n], 0, 0, 0); \
        __builtin_amdgcn_s_setprio(0);                                        \
    }

    const int NTK = K / 64;            // 32
    for (int t = 0; t < NTK - 2; t++)
        KTILE(t, "vmcnt(8)", true);
    KTILE(NTK - 2, "vmcnt(8)", false);
    KTILE(NTK - 1, "vmcnt(0)", false);

#undef KTILE
#undef GLDS

    // ---- epilogue ----
#pragma unroll
    for (int m = 0; m < 8; m++) {
        const int r0 = m0 + wm * 128 + m * 16 + quad * 4;
#pragma unroll
        for (int n = 0; n < 4; n++) {
            const int c = n0 + wn * 64 + n * 16 + l16;
#pragma unroll
            for (int r = 0; r < 4; r++)
                C[(size_t)(r0 + r) * N + c] = (bf16)acc[m][n][r];
        }
    }
}

// ---------------------------------------------------------------------------
// gemm128: C = A @ B^T, 128x256 tile, BK=64, 512 threads (8 waves, 2M x 4N,
// Wm=Wn=64).  (v8, verified; used for the f32-output projection: 256 blocks
// = 1 full round.)
// ---------------------------------------------------------------------------
template <typename CT>
__global__ __launch_bounds__(512, 2) void gemm128(
    const bf16* __restrict__ A,
    const bf16* __restrict__ B0, const bf16* __restrict__ B1, const bf16* __restrict__ B2,
    CT* __restrict__ C0, CT* __restrict__ C1, CT* __restrict__ C2,
    int M, int N, int K)
{
    const bf16* Bp = (blockIdx.z == 0) ? B0 : ((blockIdx.z == 1) ? B1 : B2);
    CT* C = (blockIdx.z == 0) ? C0 : ((blockIdx.z == 1) ? C1 : C2);

    __shared__ __align__(16) char lds[98304];

    const int wg  = blockIdx.y * 8 + blockIdx.x;
    const int swz = (wg & 7) * 32 + (wg >> 3);
    const int n0  = (swz & 7) * 256;
    const int m0  = (swz >> 3) * 128;

    const int tid  = threadIdx.x;
    const int lane = tid & 63;
    const int wave = tid >> 6;
    const int wm   = wave >> 2;
    const int wn   = wave & 3;
    const int l16  = lane & 15;
    const int quad = lane >> 4;

    f32x4 acc[4][4] = {};

    const int rA   = tid >> 2;
    const int colE = 8 * ((tid & 3) ^ ((tid >> 3) & 3));
    const bf16* pA  = A  + (size_t)(m0 + rA) * K + colE;
    const bf16* pB0 = Bp + (size_t)(n0 + rA) * K + colE;
    const bf16* pB1 = pB0 + (size_t)128 * K;
    const unsigned dstT = (unsigned)(tid * 16);
    AS3 char* ldsC = (AS3 char*)lds;

#define GLDS(src, off) \
    __builtin_amdgcn_global_load_lds((const AS1 void*)(src), (AS3 void*)(ldsC + (off)), 16, 0, 0)

    const int cOff = (quad * 16) ^ (((l16 >> 1) & 3) << 4);
    const char* sArd = (const char*)lds + (size_t)(wm * 64 + l16) * 64 + cOff;
    const char* sBrd = (const char*)lds + 16384 + (size_t)(wn * 64 + l16) * 64 + cOff;

#pragma unroll
    for (int t = 0; t < 2; t++)
#pragma unroll
        for (int kk = 0; kk < 2; kk++) {
            const size_t g = (size_t)(t * 64 + kk * 32);
            const unsigned dA = (unsigned)(t * 49152 + kk * 8192) + dstT;
            const unsigned dB = (unsigned)(t * 49152 + 16384 + kk * 16384) + dstT;
            GLDS(pA + g, dA);
            GLDS(pB0 + g, dB);
            GLDS(pB1 + g, dB + 8192);
        }

#define KTILE(T, VMSTR, DOSTAGE)                                              \
    {                                                                         \
        asm volatile("s_waitcnt " VMSTR ::: "memory");                        \
        __builtin_amdgcn_s_barrier();                                         \
        __builtin_amdgcn_sched_barrier(0);                                    \
        const int cur_ = (T) & 1;                                             \
        const char* aB_ = sArd + cur_ * 49152;                                \
        const char* bB_ = sBrd + cur_ * 49152;                                \
        bf16x8 a0[4], b0[4], a1[4], b1[4];                                    \
        _Pragma("unroll") for (int m = 0; m < 4; m++)                         \
            a0[m] = *(const bf16x8*)(aB_ + m * 1024);                         \
        _Pragma("unroll") for (int n = 0; n < 4; n++)                         \
            b0[n] = *(const bf16x8*)(bB_ + n * 1024);                         \
        _Pragma("unroll") for (int m = 0; m < 4; m++)                         \
            a1[m] = *(const bf16x8*)(aB_ + 8192 + m * 1024);                  \
        _Pragma("unroll") for (int n = 0; n < 4; n++)                         \
            b1[n] = *(const bf16x8*)(bB_ + 16384 + n * 1024);                 \
        asm volatile("s_waitcnt lgkmcnt(0)" ::: "memory");                    \
        __builtin_amdgcn_s_barrier();                                         \
        __builtin_amdgcn_sched_barrier(0);                                    \
        if (DOSTAGE) {                                                        \
            const size_t g_ = (size_t)((T) + 2) * 64;                         \
            const unsigned dA_ = (unsigned)(cur_ * 49152) + dstT;             \
            const unsigned dB_ = (unsigned)(cur_ * 49152 + 16384) + dstT;     \
            GLDS(pA + g_, dA_);                                               \
            GLDS(pB0 + g_, dB_);                                              \
            GLDS(pB1 + g_, dB_ + 8192);                                       \
            GLDS(pA + g_ + 32, dA_ + 8192);                                   \
            GLDS(pB0 + g_ + 32, dB_ + 16384);                                 \
            GLDS(pB1 + g_ + 32, dB_ + 24576);                                 \
        }                                                                     \
        __builtin_amdgcn_s_setprio(1);                                        \
        _Pragma("unroll") for (int m = 0; m < 4; m++)                         \
            _Pragma("unroll") for (int n = 0; n < 4; n++)                     \
                acc[m][n] = __builtin_amdgcn_mfma_f32_16x16x32_bf16(a0[m], b0[n], acc[m][n], 0, 0, 0); \
        _Pragma("unroll") for (int m = 0; m < 4; m++)                         \
            _Pragma("unroll") for (int n = 0; n < 4; n++)                     \
                acc[m][n] = __builtin_amdgcn_mfma_f32_16x16x32_bf16(a1[m], b1[n], acc[m][n], 0, 0, 0); \
        __builtin_amdgcn_s_setprio(0);                                        \
    }

    const int NTK = K / 64;
    for (int t = 0; t < NTK - 2; t++)
        KTILE(t, "vmcnt(6)", true);
    KTILE(NTK - 2, "vmcnt(6)", false);
    KTILE(NTK - 1, "vmcnt(0)", false);

#undef KTILE
#undef GLDS

#pragma unroll
    for (int m = 0; m < 4; m++) {
        const int r0 = m0 + wm * 64 + m * 16 + quad * 4;
#pragma unroll
        for (int n = 0; n < 4; n++) {
            const int c = n0 + wn * 64 + n * 16 + l16;
#pragma unroll
            for (int r = 0; r < 4; r++)
                C[(size_t)(r0 + r) * N + c] = (CT)acc[m][n][r];
        }
    }
}

// ---------------------------------------------------------------------------
// rope_vtrans (merged): z<32 -> vtrans slice (bh=z), z>=32 -> rope slice.
// Branch is block-uniform (z), so __syncthreads in the vtrans arm is safe.
// vtrans: V [b*S+s][h*128+d] -> Vt [(b*16+h)*128+d][s]
// rope:   one thread per (s, pair); applies rotation to 4 sites (b x {Q,K}).
// ---------------------------------------------------------------------------
__global__ __launch_bounds__(256) void rope_vtrans(
    bf16* __restrict__ Q, bf16* __restrict__ K,
    const bf16* __restrict__ V, bf16* __restrict__ Vt)
{
    const int z = blockIdx.z;
    if (z < 32) {
        // ---- vtrans ----
        __shared__ bf16 t[32][33];
        const int bh = z;
        const int s0 = blockIdx.x * 32;
        const int d0 = blockIdx.y * 32;
        const int b = bh >> 4, h = bh & 15;
        const int tx = threadIdx.x & 31, ty = threadIdx.x >> 5;

#pragma unroll
        for (int i = 0; i < 4; i++) {
            const int s = s0 + ty + i * 8;
            t[ty + i * 8][tx] = V[(size_t)(b * SEQ + s) * DMODEL + h * DK + d0 + tx];
        }
        __syncthreads();
#pragma unroll
        for (int i = 0; i < 4; i++) {
            const int d = d0 + ty + i * 8;
            Vt[(size_t)(bh * DK + d) * SEQ + s0 + tx] = t[tx][ty + i * 8];
        }
    } else {
        // ---- rope ----
        const int lb  = ((z - 32) * 4 + blockIdx.y) * 64 + blockIdx.x; // 0..8191
        const int idx = lb * 256 + threadIdx.x;
        const int pr  = idx & 1023;
        const int s   = idx >> 10;
        const int p   = pr & 63;

        // log2(10000)/64 = 0.20762050593046836
        const float ph = (float)s * exp2f(-(float)p * 0.20762050593046836f);
        float sn, cs;
        sincosf(ph, &sn, &cs);

#pragma unroll
        for (int t2 = 0; t2 < 2; t2++) {
            bf16* P = t2 ? K : Q;
#pragma unroll
            for (int b = 0; b < 2; b++) {
                bf16* ptr = P + (size_t)(b * SEQ + s) * DMODEL + pr * 2;
                bf16x2 v = *(const bf16x2*)ptr;
                const float x1 = (float)v[0], x2 = (float)v[1];
                bf16x2 r;
                r[0] = (bf16)(x1 * cs - x2 * sn);
                r[1] = (bf16)(x1 * sn + x2 * cs);
                *(bf16x2*)ptr = r;
            }
        }
    }
}

// ---------------------------------------------------------------------------
// Flash-style causal MFMA attention v4 = v3 + defer-max (T13).
// launch_bounds (256,2) -- the r8/r9-verified configuration.  v11's (256,3)
// spilled the o-accumulators to scratch (FETCH 361MB / WRITE 200MB) and
// tripled attn time; occupancy experiments on this kernel need the
// compiler-reported VGPR count as the budget check, not a hand count.
// ---------------------------------------------------------------------------
#define NEG 3.0e4f

__device__ __forceinline__ bf16* swzK(bf16* base, int row, int bcol) {
    return (bf16*)((char*)base + (((row << 8) + bcol) ^ ((row & 7) << 4)));
}
__device__ __forceinline__ const bf16* swzKc(const bf16* base, int row, int bcol) {
    return (const bf16*)((const char*)base + (((row << 8) + bcol) ^ ((row & 7) << 4)));
}
__device__ __forceinline__ bf16* swzV(bf16* base, int row, int bcol) {
    return (bf16*)((char*)base + (((row << 7) + bcol) ^ ((row & 7) << 4)));
}
__device__ __forceinline__ const bf16* swzVc(const bf16* base, int row, int bcol) {
    return (const bf16*)((const char*)base + (((row << 7) + bcol) ^ ((row & 7) << 4)));
}

__global__ __launch_bounds__(256, 2) void attn(
    const bf16* __restrict__ Q, const bf16* __restrict__ K,
    const bf16* __restrict__ Vt, bf16* __restrict__ O)
{
    const int rev = (blockIdx.y ^ blockIdx.z) & 1;
    const int qt = rev ? (gridDim.x - 1 - blockIdx.x) : blockIdx.x;
    const int h = blockIdx.y, b = blockIdx.z;
    const int tid = threadIdx.x, lane = tid & 63, wave = tid >> 6;
    const int l16 = lane & 15, quad = lane >> 4;

    __shared__ __align__(16) bf16 sK[64 * 128];
    __shared__ __align__(16) bf16 sV[128 * 64];
    __shared__ __align__(16) bf16 sP[4 * 32 * 64];

    const int q0 = qt * 128 + wave * 32;
    bf16* sPw = sP + wave * 2048;

    bf16x8 qf[2][4];
#pragma unroll
    for (int g = 0; g < 2; g++) {
        const bf16* gQ = Q + (size_t)(b * SEQ + q0 + g * 16 + l16) * DMODEL + h * DK + quad * 8;
#pragma unroll
        for (int dc = 0; dc < 4; dc++) qf[g][dc] = *(const bf16x8*)(gQ + dc * 32);
    }

    f32x4 o[2][8] = {};
    float mrow[2] = {-NEG, -NEG};
    float lrow[2] = {0.f, 0.f};

    const bf16* gK = K + (size_t)(b * SEQ) * DMODEL + h * DK;
    const bf16* gV = Vt + (size_t)((b * NH + h) * DK) * SEQ;

    const float scale = 0.12751744154470187f;
    const int nkt = 2 * qt + 2;

    const int rK = tid >> 4;
    const int cK = (tid & 15) * 8;
    const int dV = tid >> 3;
    const int cV = (tid & 7) * 8;

    bf16x8 kreg[4], vreg[4];
    {
#pragma unroll
        for (int i = 0; i < 4; i++)
            kreg[i] = *(const bf16x8*)(gK + (size_t)(rK + 16 * i) * DMODEL + cK);
#pragma unroll
        for (int i = 0; i < 4; i++)
            vreg[i] = *(const bf16x8*)(gV + (size_t)(dV + 32 * i) * SEQ + cV);
    }

    for (int kt = 0; kt < nkt; kt++) {
        __syncthreads();
#pragma unroll
        for (int i = 0; i < 4; i++)
            *(bf16x8*)swzK(sK, rK + 16 * i, cK * 2) = kreg[i];
#pragma unroll
        for (int i = 0; i < 4; i++)
            *(bf16x8*)swzV(sV, dV + 32 * i, cV * 2) = vreg[i];
        __syncthreads();

        if (kt + 1 < nkt) {
            const int kb0 = (kt + 1) * 64;
#pragma unroll
            for (int i = 0; i < 4; i++)
                kreg[i] = *(const bf16x8*)(gK + (size_t)(kb0 + rK + 16 * i) * DMODEL + cK);
#pragma unroll
            for (int i = 0; i < 4; i++)
                vreg[i] = *(const bf16x8*)(gV + (size_t)(dV + 32 * i) * SEQ + kb0 + cV);
        }

        if (kt * 64 <= q0 + 15) {
            f32x4 s4[2][4] = {};
            __builtin_amdgcn_s_setprio(1);
#pragma unroll
            for (int sub = 0; sub < 4; sub++)
#pragma unroll
                for (int dc = 0; dc < 4; dc++) {
                    bf16x8 kb = *(const bf16x8*)swzKc(sK, sub * 16 + l16, dc * 64 + quad * 16);
                    s4[0][sub] = __builtin_amdgcn_mfma_f32_16x16x32_bf16(kb, qf[0][dc], s4[0][sub], 0, 0, 0);
                    s4[1][sub] = __builtin_amdgcn_mfma_f32_16x16x32_bf16(kb, qf[1][dc], s4[1][sub], 0, 0, 0);
                }
            __builtin_amdgcn_s_setprio(0);

#pragma unroll
            for (int g = 0; g < 2; g++) {
                const int qg = q0 + g * 16 + l16;
                const int kb0 = kt * 64 + quad * 4;
                float arr[16];
                float mx = -NEG;
#pragma unroll
                for (int sub = 0; sub < 4; sub++)
#pragma unroll
                    for (int r = 0; r < 4; r++) {
                        const int key = kb0 + sub * 16 + r;
                        const float val = (key <= qg) ? s4[g][sub][r] * scale : -NEG;
                        arr[sub * 4 + r] = val;
                        mx = fmaxf(mx, val);
                    }
                mx = fmaxf(mx, __shfl_xor(mx, 16));
                mx = fmaxf(mx, __shfl_xor(mx, 32));

                // T13 defer-max: rescale only when some row's max grew by >8
                // (P then bounded by 2^8; f32 accum headroom fine).
                float alpha = 1.0f;
                if (__any(mx - mrow[g] > 8.0f)) {
                    const float mnew = fmaxf(mrow[g], mx);
                    alpha = exp2f(mrow[g] - mnew);
                    mrow[g] = mnew;
#pragma unroll
                    for (int r = 0; r < 4; r++) {
                        const float ar = __shfl(alpha, quad * 4 + r, 16);
#pragma unroll
                        for (int dt = 0; dt < 8; dt++) o[g][dt][r] *= ar;
                    }
                }
                float ps = 0.f;
#pragma unroll
                for (int i = 0; i < 16; i++) {
                    arr[i] = exp2f(arr[i] - mrow[g]);
                    ps += arr[i];
                }
                ps += __shfl_xor(ps, 16);
                ps += __shfl_xor(ps, 32);
                lrow[g] = lrow[g] * alpha + ps;

#pragma unroll
                for (int sub = 0; sub < 4; sub++) {
                    bf16x4 pk;
                    pk[0] = (bf16)arr[sub * 4 + 0];
                    pk[1] = (bf16)arr[sub * 4 + 1];
                    pk[2] = (bf16)arr[sub * 4 + 2];
                    pk[3] = (bf16)arr[sub * 4 + 3];
                    *(bf16x4*)swzV(sPw, g * 16 + l16, sub * 32 + quad * 8) = pk;
                }
            }

            asm volatile("s_waitcnt lgkmcnt(0)" ::: "memory");
            __builtin_amdgcn_sched_barrier(0);

            bf16x8 pf0[2], pf1[2];
#pragma unroll
            for (int g = 0; g < 2; g++) {
                pf0[g] = *(const bf16x8*)swzVc(sPw, g * 16 + l16, quad * 16);
                pf1[g] = *(const bf16x8*)swzVc(sPw, g * 16 + l16, 64 + quad * 16);
            }
            __builtin_amdgcn_s_setprio(1);
#pragma unroll
            for (int dt = 0; dt < 8; dt++) {
                bf16x8 vf0 = *(const bf16x8*)swzVc(sV, dt * 16 + l16, quad * 16);
                bf16x8 vf1 = *(const bf16x8*)swzVc(sV, dt * 16 + l16, 64 + quad * 16);
                o[0][dt] = __builtin_amdgcn_mfma_f32_16x16x32_bf16(pf0[0], vf0, o[0][dt], 0, 0, 0);
                o[0][dt] = __builtin_amdgcn_mfma_f32_16x16x32_bf16(pf1[0], vf1, o[0][dt], 0, 0, 0);
                o[1][dt] = __builtin_amdgcn_mfma_f32_16x16x32_bf16(pf0[1], vf0, o[1][dt], 0, 0, 0);
                o[1][dt] = __builtin_amdgcn_mfma_f32_16x16x32_bf16(pf1[1], vf1, o[1][dt], 0, 0, 0);
            }
            __builtin_amdgcn_s_setprio(0);
        }
    }

#pragma unroll
    for (int g = 0; g < 2; g++) {
        bf16* gO = O + (size_t)(b * SEQ + q0 + g * 16 + quad * 4) * DMODEL + h * DK + l16;
#pragma unroll
        for (int r = 0; r < 4; r++) {
            const float lr = __shfl(lrow[g], quad * 4 + r, 16);
            const float inv = 1.0f / lr;
#pragma unroll
            for (int dt = 0; dt < 8; dt++)
                gO[(size_t)r * DMODEL + dt * 16] = (bf16)(o[g][dt][r] * inv);
        }
    }
}

// ---------------------------------------------------------------------------
extern "C" void kernel_launch(void* const* d_in, const int* in_sizes, int n_in,
                              void* d_out, int out_size, void* d_ws, size_t ws_size,
                              hipStream_t stream)
{
    const float* x  = (const float*)d_in[0];
    const float* Wq = (const float*)d_in[2];
    const float* Wk = (const float*)d_in[3];
    const float* Wv = (const float*)d_in[4];
    const float* Wo = (const float*)d_in[5];

    const int M = 2 * SEQ;       // 4096
    const int N = DMODEL;        // 2048
    const int Kd = DMODEL;       // 2048
    const size_t tsz = (size_t)M * N;   // 8.4M elems
    const size_t wsz = (size_t)N * Kd;  // 4.2M elems

    // Workspace layout (bf16): xb | Wqb Wkb Wvb Wob | Qb Kb Vb  = 100.7 MB
    bf16* xb  = (bf16*)d_ws;
    bf16* Wqb = xb  + tsz;
    bf16* Wkb = Wqb + wsz;
    bf16* Wvb = Wkb + wsz;
    bf16* Wob = Wvb + wsz;
    bf16* Qb  = Wob + wsz;
    bf16* Kb  = Qb  + tsz;
    bf16* Vb  = Kb  + tsz;
    bf16* Vt  = (bf16*)d_out;    // scratch in d_out; fully overwritten by
                                 // the final f32 GEMM stores
    bf16* Ab  = Vb;              // alias: Vb dead once Vt is built

    // 0) cast all f32 inputs to bf16
    cast_f32_bf16<<<dim3(tsz / 1024, 1, 5), 256, 0, stream>>>(
        x, Wq, Wk, Wv, Wo, xb, Wqb, Wkb, Wvb, Wob);

    // 1) Q,K,V projections: exact-v5 256^2 GEMM (512 threads)
    gemm256<<<dim3(N / 256, M / 256, 3), 512, 0, stream>>>(
        xb, Wqb, Wkb, Wvb, Qb, Kb, Vb, M, N, Kd);

    // 2) merged RoPE (Q,K) + V transpose: z<32 vtrans, z>=32 rope
    rope_vtrans<<<dim3(64, 4, 64), 256, 0, stream>>>(Qb, Kb, Vb, Vt);

    // 3) causal flash attention -> Ab (Vb's storage)
    attn<<<dim3(SEQ / 128, NH, 2), 256, 0, stream>>>(Qb, Kb, Vt, Ab);

    // 4) output projection: gemm128<float>, 256 blocks = 1 full round
    gemm128<float><<<dim3(N / 256, M / 128, 1), 512, 0, stream>>>(
        Ab, Wob, Wob, Wob, (float*)d_out, (float*)d_out, (float*)d_out, M, N, Kd);
}